// Round 4
// baseline (89.072 us; speedup 1.0000x reference)
//
#include <hip/hip_runtime.h>
#include <hip/hip_bf16.h>

#define DD 512
#define NN 8
#define LL0 128
#define LL1 256

// 2 * log2(e): pre-scale factor so tanh(t) can use v_exp_f32 (2^x) directly.
#define LOG2E2 2.8853900817779268f

// split-K partial plane stride (floats): 3072 rows x 512 e
#define PSTR ((size_t)3072 * 512)

__device__ __forceinline__ float fexp2(float x) {
#if __has_builtin(__builtin_amdgcn_exp2f)
    return __builtin_amdgcn_exp2f(x);
#else
    float r; asm("v_exp_f32 %0, %1" : "=v"(r) : "v"(x)); return r;
#endif
}
__device__ __forceinline__ float frcp(float x) {
#if __has_builtin(__builtin_amdgcn_rcpf)
    return __builtin_amdgcn_rcpf(x);
#else
    float r; asm("v_rcp_f32 %0, %1" : "=v"(r) : "v"(x)); return r;
#endif
}

// sigma2(t2) = 1/(2^t2 + 1), where t2 = 2*log2e*t.  tanh(t) = 1 - 2*sigma2.
__device__ __forceinline__ float sig2(float t2) {
    return frcp(fexp2(t2) + 1.0f);
}

// ---------------------------------------------------------------------------
// Kernel 1: fused projections, split-K=2.  (round-2 version: measured ~34 us)
// pp[kz][row][e] = sum_{k in half kz} A[row,k] * W[e, koff+k]
// Tile 64(M) x 64(e), K-chunk 32, 256 threads, 4x4 micro-tile.
// LDS tiles TRANSPOSED [k][row] (pad 68) -> inner reads are 2x ds_read_b128.
// Grid (48, 8, 2) = 768 blocks = 3.0/CU exact.
// ---------------------------------------------------------------------------
__global__ __launch_bounds__(256, 3) void proj_kernel(
    const float* __restrict__ x, const float* __restrict__ m,
    const float* __restrict__ W, float* __restrict__ pp)
{
    __shared__ float At[32][68];
    __shared__ float Bt[32][68];

    int row0 = blockIdx.x * 64;
    int e0   = blockIdx.y * 64;
    int kb   = blockIdx.z * 256;   // K-half base

    bool isx = row0 < (NN * LL0);
    const float* A  = (isx ? x + (size_t)row0 * DD
                           : m + (size_t)(row0 - NN * LL0) * DD) + kb;
    const float* Wp = W + (size_t)e0 * (2 * DD) + (isx ? 0 : DD) + kb;

    int t  = threadIdx.x;
    int lr = t >> 2;              // 0..63 : staging row (A) / e-row (B)
    int kc = (t & 3) * 8;         // 0,8,16,24 : k-offset within 32-chunk
    int ty = t >> 4, tx = t & 15;

    const float* Ap = A  + (size_t)lr * DD + kc;
    const float* Bp = Wp + (size_t)lr * (2 * DD) + kc;

    float4 ar0 = *(const float4*)(Ap);
    float4 ar1 = *(const float4*)(Ap + 4);
    float4 br0 = *(const float4*)(Bp);
    float4 br1 = *(const float4*)(Bp + 4);

    float acc[4][4] = {};

    for (int kt = 0; kt < 8; ++kt) {
        if (kt) __syncthreads();
        At[kc + 0][lr] = ar0.x; At[kc + 1][lr] = ar0.y;
        At[kc + 2][lr] = ar0.z; At[kc + 3][lr] = ar0.w;
        At[kc + 4][lr] = ar1.x; At[kc + 5][lr] = ar1.y;
        At[kc + 6][lr] = ar1.z; At[kc + 7][lr] = ar1.w;
        Bt[kc + 0][lr] = br0.x; Bt[kc + 1][lr] = br0.y;
        Bt[kc + 2][lr] = br0.z; Bt[kc + 3][lr] = br0.w;
        Bt[kc + 4][lr] = br1.x; Bt[kc + 5][lr] = br1.y;
        Bt[kc + 6][lr] = br1.z; Bt[kc + 7][lr] = br1.w;
        if (kt < 7) {
            int ko = (kt + 1) * 32;
            ar0 = *(const float4*)(Ap + ko);
            ar1 = *(const float4*)(Ap + ko + 4);
            br0 = *(const float4*)(Bp + ko);
            br1 = *(const float4*)(Bp + ko + 4);
        }
        __syncthreads();

        #pragma unroll
        for (int kk = 0; kk < 32; ++kk) {
            float4 av = *(const float4*)&At[kk][ty * 4];
            float4 bv = *(const float4*)&Bt[kk][tx * 4];
            acc[0][0] = fmaf(av.x, bv.x, acc[0][0]);
            acc[0][1] = fmaf(av.x, bv.y, acc[0][1]);
            acc[0][2] = fmaf(av.x, bv.z, acc[0][2]);
            acc[0][3] = fmaf(av.x, bv.w, acc[0][3]);
            acc[1][0] = fmaf(av.y, bv.x, acc[1][0]);
            acc[1][1] = fmaf(av.y, bv.y, acc[1][1]);
            acc[1][2] = fmaf(av.y, bv.z, acc[1][2]);
            acc[1][3] = fmaf(av.y, bv.w, acc[1][3]);
            acc[2][0] = fmaf(av.z, bv.x, acc[2][0]);
            acc[2][1] = fmaf(av.z, bv.y, acc[2][1]);
            acc[2][2] = fmaf(av.z, bv.z, acc[2][2]);
            acc[2][3] = fmaf(av.z, bv.w, acc[2][3]);
            acc[3][0] = fmaf(av.w, bv.x, acc[3][0]);
            acc[3][1] = fmaf(av.w, bv.y, acc[3][1]);
            acc[3][2] = fmaf(av.w, bv.z, acc[3][2]);
            acc[3][3] = fmaf(av.w, bv.w, acc[3][3]);
        }
    }

    float* outp = pp + (size_t)blockIdx.z * PSTR
                     + (size_t)row0 * DD + e0 + tx * 4;
    #pragma unroll
    for (int i = 0; i < 4; ++i) {
        float4 v = make_float4(acc[i][0], acc[i][1], acc[i][2], acc[i][3]);
        *(float4*)(outp + (size_t)(ty * 4 + i) * DD) = v;
    }
}

// ---------------------------------------------------------------------------
// Kernel 1b: split-K reduce (2 planes) + bias + LOG2E2 scale.
// ---------------------------------------------------------------------------
__global__ __launch_bounds__(256) void reduce_kernel(
    const float* __restrict__ pp, const float* __restrict__ Wb,
    float* __restrict__ xpb_base)
{
    size_t f = (size_t)blockIdx.x * 256 + threadIdx.x;   // float4 index
    const float4* p4 = (const float4*)pp;
    float4 v0 = p4[f];
    float4 v1 = p4[f + PSTR / 4];
    float4 s = make_float4(v0.x + v1.x, v0.y + v1.y, v0.z + v1.z, v0.w + v1.w);
    size_t off = f * 4;
    if (off < (size_t)NN * LL0 * DD) {   // x-rows: add bias
        float4 wb = *(const float4*)(Wb + (off & (DD - 1)));
        s.x += wb.x; s.y += wb.y; s.z += wb.z; s.w += wb.w;
    }
    s.x *= LOG2E2; s.y *= LOG2E2; s.z *= LOG2E2; s.w *= LOG2E2;
    ((float4*)xpb_base)[f] = s;
}

// ---------------------------------------------------------------------------
// Kernel 2: logits partials — 64a x 64b tile, 4x4 micro-tile, d-chunk 32.
//   wpart[dc][n][a][b] = sum_{d in chunk dc} V[d] / (2^(xpb[n,a,d]+mp[n,b,d]) + 1)
// LDS tiles TRANSPOSED [d][a] (pad 68): per kk, a-frag = one b128 (4-addr
// broadcast, conflict-free), b-frag = one b128 (2-way, free), V = broadcast.
// LDS traffic: 128 B/wave-elem = 1 cyc/wave-elem (was 2.5).
// Grid (4, 32, 8) = 1024 blocks = 4.0/CU exact; LDS 17.4 KB; 16 waves/CU.
// ---------------------------------------------------------------------------
__global__ __launch_bounds__(256, 4) void logits_kernel(
    const float* __restrict__ xpb, const float* __restrict__ mp,
    const float* __restrict__ Vw,
    float* __restrict__ wpart)
{
    __shared__ __attribute__((aligned(16))) float xs[32][68];  // [d][a]
    __shared__ __attribute__((aligned(16))) float ms[32][68];  // [d][b]
    __shared__ __attribute__((aligned(16))) float vsh[32];

    int n  = blockIdx.z;
    int bt = blockIdx.x;          // 0..3 (64 b-cols each)
    int at = blockIdx.y & 1;      // 0..1 (64 a-rows each)
    int dc = blockIdx.y >> 1;     // 0..15 (d-chunk of 32)
    int tid = threadIdx.x;
    int ty = tid >> 4, tx = tid & 15;

    const float* xrow = xpb + (size_t)(n * LL0 + at * 64) * DD + dc * 32;
    const float* mrow = mp  + (size_t)(n * LL1 + bt * 64) * DD + dc * 32;

    // stage transposed: thread (r = tid>>2, c8 = (tid&3)*8) loads 8 d's of row r
    {
        int r  = tid >> 2;            // 0..63
        int c8 = (tid & 3) * 8;       // 0,8,16,24
        float4 xv0 = *(const float4*)(xrow + (size_t)r * DD + c8);
        float4 xv1 = *(const float4*)(xrow + (size_t)r * DD + c8 + 4);
        float4 mv0 = *(const float4*)(mrow + (size_t)r * DD + c8);
        float4 mv1 = *(const float4*)(mrow + (size_t)r * DD + c8 + 4);
        xs[c8 + 0][r] = xv0.x; xs[c8 + 1][r] = xv0.y;
        xs[c8 + 2][r] = xv0.z; xs[c8 + 3][r] = xv0.w;
        xs[c8 + 4][r] = xv1.x; xs[c8 + 5][r] = xv1.y;
        xs[c8 + 6][r] = xv1.z; xs[c8 + 7][r] = xv1.w;
        ms[c8 + 0][r] = mv0.x; ms[c8 + 1][r] = mv0.y;
        ms[c8 + 2][r] = mv0.z; ms[c8 + 3][r] = mv0.w;
        ms[c8 + 4][r] = mv1.x; ms[c8 + 5][r] = mv1.y;
        ms[c8 + 6][r] = mv1.z; ms[c8 + 7][r] = mv1.w;
        if (tid < 8)
            *(float4*)&vsh[tid * 4] = *(const float4*)(Vw + dc * 32 + tid * 4);
    }
    __syncthreads();

    float acc[4][4] = {};

    #pragma unroll 8
    for (int kk = 0; kk < 32; ++kk) {
        float4 xa = *(const float4*)&xs[kk][ty * 4];   // 4 a-values
        float4 mb = *(const float4*)&ms[kk][tx * 4];   // 4 b-values
        float  vv = vsh[kk];
        float b_[4] = {mb.x, mb.y, mb.z, mb.w};
        float a_[4] = {xa.x, xa.y, xa.z, xa.w};
        #pragma unroll
        for (int i = 0; i < 4; ++i)
            #pragma unroll
            for (int j = 0; j < 4; ++j)
                acc[i][j] = fmaf(vv, sig2(a_[i] + b_[j]), acc[i][j]);
    }

    float* wp = wpart + ((size_t)dc * NN + n) * (size_t)(LL0 * LL1);
    int a = at * 64 + ty * 4;
    int b = bt * 64 + tx * 4;
    #pragma unroll
    for (int i = 0; i < 4; ++i) {
        float4 v = make_float4(acc[i][0], acc[i][1], acc[i][2], acc[i][3]);
        *(float4*)(wp + (size_t)(a + i) * LL1 + b) = v;
    }
}

// ---------------------------------------------------------------------------
// Kernel 3: masked softmax over b (sums 16 d-chunk partials, -2 scale).
// ---------------------------------------------------------------------------
__global__ __launch_bounds__(256) void softmax_kernel(
    float* __restrict__ wbuf, const int* __restrict__ mask)
{
    __shared__ float red[4];
    __shared__ float red2[4];
    const size_t P = (size_t)NN * LL0 * LL1;
    int row = blockIdx.x;          // n*L0 + a
    int n = row >> 7;
    int b = threadIdx.x;
    size_t idx = (size_t)row * LL1 + b;

    float s16 = 0.f;
    #pragma unroll
    for (int p = 0; p < 16; ++p) s16 += wbuf[idx + (size_t)p * P];
    float w = -2.0f * s16;
    if (mask[n * LL1 + b] == 0) w = -1e12f;

    float mx = w;
    #pragma unroll
    for (int off = 32; off; off >>= 1) mx = fmaxf(mx, __shfl_xor(mx, off));
    int wv = threadIdx.x >> 6;
    if ((threadIdx.x & 63) == 0) red[wv] = mx;
    __syncthreads();
    mx = fmaxf(fmaxf(red[0], red[1]), fmaxf(red[2], red[3]));

    float e = __expf(w - mx);
    float s = e;
    #pragma unroll
    for (int off = 32; off; off >>= 1) s += __shfl_xor(s, off);
    if ((threadIdx.x & 63) == 0) red2[wv] = s;
    __syncthreads();
    s = red2[0] + red2[1] + red2[2] + red2[3];

    wbuf[idx] = e / s;
}

// ---------------------------------------------------------------------------
// Kernel 4: v[n,a,d] = sum_b w[n,a,b] * m[n,b,d]. (unchanged)
// ---------------------------------------------------------------------------
__global__ __launch_bounds__(256) void vgemm_kernel(
    const float* __restrict__ wbuf, const float* __restrict__ m,
    float* __restrict__ out)
{
    __shared__ float ws_t[64][17];
    __shared__ float ms_t[16][65];

    int n = blockIdx.z;
    int a0 = blockIdx.y * 64;
    int d0 = blockIdx.x * 64;
    int tid = threadIdx.x;
    int ty = tid >> 4, tx = tid & 15;

    const float* wrow = wbuf + ((size_t)n * LL0 + a0) * LL1;
    const float* mrow = m + (size_t)n * LL1 * DD;

    float acc[4][4] = {};
    for (int k0 = 0; k0 < LL1; k0 += 16) {
        {
            int lr = tid >> 2, lc = (tid & 3) * 4;
            float4 wv = *(const float4*)(wrow + (size_t)lr * LL1 + k0 + lc);
            ws_t[lr][lc + 0] = wv.x; ws_t[lr][lc + 1] = wv.y;
            ws_t[lr][lc + 2] = wv.z; ws_t[lr][lc + 3] = wv.w;
        }
        {
            int lr = tid >> 4, lc = (tid & 15) * 4;
            float4 mv = *(const float4*)(mrow + (size_t)(k0 + lr) * DD + d0 + lc);
            ms_t[lr][lc + 0] = mv.x; ms_t[lr][lc + 1] = mv.y;
            ms_t[lr][lc + 2] = mv.z; ms_t[lr][lc + 3] = mv.w;
        }
        __syncthreads();
        #pragma unroll
        for (int kk = 0; kk < 16; ++kk) {
            float a_[4], b_[4];
            #pragma unroll
            for (int i = 0; i < 4; ++i) a_[i] = ws_t[ty * 4 + i][kk];
            #pragma unroll
            for (int j = 0; j < 4; ++j) b_[j] = ms_t[kk][tx * 4 + j];
            #pragma unroll
            for (int i = 0; i < 4; ++i)
                #pragma unroll
                for (int j = 0; j < 4; ++j)
                    acc[i][j] = fmaf(a_[i], b_[j], acc[i][j]);
        }
        __syncthreads();
    }
    #pragma unroll
    for (int i = 0; i < 4; ++i)
        #pragma unroll
        for (int j = 0; j < 4; ++j)
            out[((size_t)n * LL0 + a0 + ty * 4 + i) * DD + d0 + tx * 4 + j] = acc[i][j];
}

extern "C" void kernel_launch(void* const* d_in, const int* in_sizes, int n_in,
                              void* d_out, int out_size, void* d_ws, size_t ws_size,
                              hipStream_t stream) {
    const float* x    = (const float*)d_in[0];
    const float* m    = (const float*)d_in[1];
    const int*   mask = (const int*)d_in[2];
    const float* W_w  = (const float*)d_in[3];
    const float* W_b  = (const float*)d_in[4];
    const float* V_w  = (const float*)d_in[5];
    const float* V_b  = (const float*)d_in[6];
    (void)V_b; // additive constant — cancels under softmax shift-invariance
    float* out = (float*)d_out;

    // Workspace layout (floats):
    //   xpb    : 8*128*512            =  524288
    //   mp     : 8*256*512            = 1048576   (contiguous after xpb)
    //   region : max(pp 2*3072*512 = 3145728, wpart 16*8*128*256 = 4194304)
    // pp (split-K partials) is dead after reduce_kernel; wpart aliases it.
    // Total: 5,767,168 floats = 23.1 MB
    float* xpb    = (float*)d_ws;
    float* mp     = xpb + (size_t)NN * LL0 * DD;
    float* region = mp + (size_t)NN * LL1 * DD;
    float* pp     = region;
    float* wpart  = region;

    proj_kernel<<<dim3(48, 8, 2), 256, 0, stream>>>(x, m, W_w, pp);
    reduce_kernel<<<dim3(1536), 256, 0, stream>>>(pp, W_b, xpb);
    logits_kernel<<<dim3(4, 32, 8), 256, 0, stream>>>(xpb, mp, V_w, wpart);
    softmax_kernel<<<dim3(1024), 256, 0, stream>>>(wpart, mask);
    vgemm_kernel<<<dim3(8, 2, 8), 256, 0, stream>>>(wpart, m, out);
}